// Round 6
// baseline (269.746 us; speedup 1.0000x reference)
//
#include <hip/hip_runtime.h>

constexpr int VIEWS = 360;
constexpr int IMGSZ = 512;
constexpr int BATCH = 2;
constexpr int WCHUNK = 64;   // w per block
constexpr int KH = 64;       // h per LDS chunk
constexpr int NXF4 = 25;     // staged box width in float4 (100 floats)
constexpr int MAXNY = 94;    // max staged rows: 63*(|s|+|c|)+4 <= 93.2
constexpr int MAXP = 108;    // max selectable pitch (mult of 4; 108*94*4 = 40608 B)
constexpr int PW = 712;      // padded image width  (mult of 4)
constexpr int PH = 704;      // padded image height
constexpr int PAD = 96;
constexpr size_t PAD_BYTES = (size_t)BATCH * PH * PW * 4;   // 4,009,984

// ---------- pad kernel: zero-padded copy of both images into d_ws ----------
__global__ __launch_bounds__(256) void pad_kernel(const float* __restrict__ x,
                                                  float* __restrict__ pad) {
    constexpr int rowf4 = PW / 4;
    constexpr int perimg = PH * rowf4;
    int idx = blockIdx.x * 256 + threadIdx.x;
    if (idx >= BATCH * perimg) return;
    int b = idx / perimg;
    int r = idx - b * perimg;
    int py = r / rowf4;
    int px4 = r - py * rowf4;
    int gx = px4 * 4 - PAD;
    int gy = py - PAD;
    float4 v = make_float4(0.f, 0.f, 0.f, 0.f);
    if ((unsigned)gy < (unsigned)IMGSZ && (unsigned)gx < (unsigned)IMGSZ)
        v = *(const float4*)(x + ((size_t)b * IMGSZ + gy) * IMGSZ + gx);
    *(float4*)(pad + (size_t)idx * 4) = v;
}

// ---------- prep kernel: per-view LDS pitch minimizing bank conflicts ------
// One wave per view. Lane i simulates gather lane i (w = 128+i); banks are
// (ly*P + lx) & 31 -- x_lo/y_lo shift banks by a constant, so omitting them
// is exact for conflict counting. Score = sum over banks of lanes beyond the
// free 2-way, at 3 representative h values.
__global__ __launch_bounds__(64) void prep_kernel(int* __restrict__ pitchTab) {
    int v = blockIdx.x;
    int lane = threadIdx.x;
    double ang = -3.14159265358979323846 * (double)(v + 1) / (double)VIEWS
                 - 3.14159265358979323846;
    float c = (float)cos(ang);
    float s = (float)sin(ang);
    float xw = (float)(128 + lane) + 0.5f - 256.0f;
    float cxw = c * xw;
    float sxw = s * xw;

    int bestP = 100, bestBad = 0x7fffffff;
    for (int P = 100; P <= MAXP; P += 4) {
        int bad = 0;
        #pragma unroll
        for (int t = 0; t < 3; ++t) {
            float hh = (float)(40 + 21 * t) - 255.5f;
            int lx = (int)floorf(fmaf(-s, hh, cxw));
            int ly = (int)floorf(fmaf(c, hh, sxw));
            int bank = (ly * P + lx) & 31;
            for (int b = 0; b < 32; ++b) {
                unsigned long long m = __ballot(bank == b);
                int cnt = __popcll(m);
                bad += max(0, cnt - 2);
            }
        }
        if (bad < bestBad) { bestBad = bad; bestP = P; }
    }
    if (lane == 0) pitchTab[v] = bestP;
}

// ---------- main kernel ----------
__global__ __launch_bounds__(256) void fp_kernel(const float* __restrict__ pad,
                                                 const int* __restrict__ pitchTab,
                                                 float* __restrict__ out) {
    __shared__ __align__(16) float tile[MAXP * MAXNY];   // 40608 B, 4 blocks/CU

    int blk = blockIdx.x;
    int wc = blk & 7;
    int bv = blk >> 3;
    int v = bv % VIEWS;
    int b = bv / VIEWS;

    int tid = threadIdx.x;
    int lane = tid & 63;
    int g = tid >> 6;
    int w = wc * WCHUNK + lane;

    int P = pitchTab[v];   // block-uniform -> scalar load

    double ang = -3.14159265358979323846 * (double)(v + 1) / (double)VIEWS
                 - 3.14159265358979323846;
    float c = (float)cos(ang);
    float s = (float)sin(ang);

    const float* __restrict__ pimg = pad + (size_t)b * PH * PW;

    float xw = (float)w + 0.5f - 256.0f;
    float cxw = fmaf(c, xw, 255.5f);
    float sxw = fmaf(s, xw, 255.5f);

    // Per-thread valid-h interval (identical to validated rounds 2-5).
    float lo = -1e30f, hi = 1e30f;
    {
        float coef = -s, base = cxw;
        if (fabsf(coef) > 1e-6f) {
            float a = (-1.0f - base) / coef;
            float bq = (512.0f - base) / coef;
            lo = fmaxf(lo, fminf(a, bq));
            hi = fminf(hi, fmaxf(a, bq));
        } else if (!(base > -1.0f && base < 512.0f)) {
            lo = 1e30f; hi = -1e30f;
        }
    }
    {
        float coef = c, base = sxw;
        if (fabsf(coef) > 1e-6f) {
            float a = (-1.0f - base) / coef;
            float bq = (512.0f - base) / coef;
            lo = fmaxf(lo, fminf(a, bq));
            hi = fminf(hi, fmaxf(a, bq));
        } else if (!(base > -1.0f && base < 512.0f)) {
            lo = 1e30f; hi = -1e30f;
        }
    }
    float h0f = fminf(fmaxf(floorf(lo + 255.5f) - 1.0f, 0.0f), 512.0f);
    float h1f = fminf(fmaxf(ceilf(hi + 255.5f) + 1.0f, -1.0f), 511.0f);
    int h0 = (int)h0f;
    int h1 = (int)h1f;

    int bh0 = h0, bh1 = h1;
    #pragma unroll
    for (int m = 1; m < 64; m <<= 1) {
        bh0 = min(bh0, __shfl_xor(bh0, m, 64));
        bh1 = max(bh1, __shfl_xor(bh1, m, 64));
    }

    float xa = (float)(wc * WCHUNK) + 0.5f - 256.0f;
    float xb = xa + 63.0f;

    float acc = 0.0f;
    float step4x = -4.0f * s;
    float step4y = 4.0f * c;

    for (int hc = bh0; hc <= bh1; hc += KH) {
        int hend = min(hc + KH - 1, bh1);

        float ha = (float)hc - 255.5f;
        float hb = (float)hend - 255.5f;
        float ix00 = c * xa - s * ha, ix01 = c * xa - s * hb;
        float ix10 = c * xb - s * ha, ix11 = c * xb - s * hb;
        float iy00 = s * xa + c * ha, iy01 = s * xa + c * hb;
        float iy10 = s * xb + c * ha, iy11 = s * xb + c * hb;
        float ixmn = fminf(fminf(ix00, ix01), fminf(ix10, ix11)) + 255.5f;
        float iymn = fminf(fminf(iy00, iy01), fminf(iy10, iy11)) + 255.5f;
        float iymx = fmaxf(fmaxf(iy00, iy01), fmaxf(iy10, iy11)) + 255.5f;
        int x_lo = (int)floorf(ixmn) - 1;
        int x_lo4 = x_lo & ~3;
        int y_lo = (int)floorf(iymn) - 1;
        int NY = min((int)floorf(iymx) + 3 - y_lo, MAXNY);
        int total4 = NY * NXF4;
        int nit = (total4 + 255) >> 8;

        __syncthreads();

        // Maskless float4 staging from padded image; LDS rows of 100 floats
        // at runtime pitch P (mult of 4 -> b128-aligned writes).
        {
            const float* pb = pimg + (y_lo + PAD) * PW + (x_lo4 + PAD);
            for (int k = 0; k < nit; ++k) {
                int i = (k << 8) + tid;
                int ic = min(i, total4 - 1);
                int ry = ic / NXF4;                   // magic-mul (const 25)
                int rx4 = ic - ry * NXF4;
                float4 val = *(const float4*)(pb + 4 * ic + (PW - 4 * NXF4) * ry);
                *(float4*)&tile[ry * P + (rx4 << 2)] = val;
            }
        }
        __syncthreads();

        // Maskless clampless gather; wave g handles h = hc+g, +4, ...
        float hh0 = (float)(hc + g) - 255.5f;
        float ixr = fmaf(-s, hh0, cxw) - (float)x_lo4;
        float iyr = fmaf(c, hh0, sxw) - (float)y_lo;
        #pragma unroll 4
        for (int h = hc + g; h <= hend; h += 4) {
            float fx = floorf(ixr);
            float fy = floorf(iyr);
            int lx = (int)fx;
            int ly = (int)fy;
            float wx1 = ixr - fx;
            float wy1 = iyr - fy;
            const float* p = tile + (ly * P + lx);
            const float* q = p + P;
            float t00 = p[0];
            float t01 = p[1];
            float t10 = q[0];
            float t11 = q[1];
            float l0 = fmaf(wx1, t01 - t00, t00);
            float l1 = fmaf(wx1, t11 - t10, t10);
            acc = fmaf(wy1, l1 - l0, acc + l0);
            ixr += step4x;
            iyr += step4y;
        }
    }

    // Reduce the 4 h-phase partials, reusing the tile.
    __syncthreads();
    tile[(g << 6) + lane] = acc;
    __syncthreads();
    if (g == 0) {
        float r = tile[lane] + tile[64 + lane] + tile[128 + lane] + tile[192 + lane];
        out[((size_t)(b * IMGSZ + w)) * VIEWS + v] = r * 0.5f;
    }
}

extern "C" void kernel_launch(void* const* d_in, const int* in_sizes, int n_in,
                              void* d_out, int out_size, void* d_ws, size_t ws_size,
                              hipStream_t stream) {
    const float* x = (const float*)d_in[0];
    float* out = (float*)d_out;
    float* pad = (float*)d_ws;
    int* pitchTab = (int*)((char*)d_ws + PAD_BYTES);   // 360 ints after pad

    constexpr int padTotal = BATCH * PH * (PW / 4);
    pad_kernel<<<(padTotal + 255) / 256, 256, 0, stream>>>(x, pad);
    prep_kernel<<<VIEWS, 64, 0, stream>>>(pitchTab);

    int nblocks = BATCH * VIEWS * (IMGSZ / WCHUNK);   // 5760
    fp_kernel<<<nblocks, 256, 0, stream>>>(pad, pitchTab, out);
}

// Round 7
// 246.755 us; speedup vs baseline: 1.0932x; 1.0932x over previous
//
#include <hip/hip_runtime.h>
#include <hip/hip_bf16.h>

constexpr int VIEWS = 360;
constexpr int IMGSZ = 512;
constexpr int BATCH = 2;
constexpr int WCHUNK = 64;   // w per block
constexpr int KH = 64;       // h per LDS chunk
constexpr int NXF4 = 25;     // staged box width in float4 (100 texels)
constexpr int PITCH = 100;   // LDS row pitch in dwords (pairs), compile-time
constexpr int MAXNY = 94;    // max staged rows: 63*(|s|+|c|)+4 <= 93.2
constexpr int PW = 712;      // padded image width  (mult of 4)
constexpr int PH = 704;      // padded image height
constexpr int PAD = 96;

// ---------- pad kernel: zero-padded copy of both images into d_ws ----------
__global__ __launch_bounds__(256) void pad_kernel(const float* __restrict__ x,
                                                  float* __restrict__ pad) {
    constexpr int rowf4 = PW / 4;
    constexpr int perimg = PH * rowf4;
    int idx = blockIdx.x * 256 + threadIdx.x;
    if (idx >= BATCH * perimg) return;
    int b = idx / perimg;
    int r = idx - b * perimg;
    int py = r / rowf4;
    int px4 = r - py * rowf4;
    int gx = px4 * 4 - PAD;
    int gy = py - PAD;
    float4 v = make_float4(0.f, 0.f, 0.f, 0.f);
    if ((unsigned)gy < (unsigned)IMGSZ && (unsigned)gx < (unsigned)IMGSZ)
        v = *(const float4*)(x + ((size_t)b * IMGSZ + gy) * IMGSZ + gx);
    *(float4*)(pad + (size_t)idx * 4) = v;
}

// ---------- main kernel: bf16-pair tile, 2 LDS reads per bilinear tap ------
__global__ __launch_bounds__(256) void fp_kernel(const float* __restrict__ pad,
                                                 float* __restrict__ out) {
    // tileU[y*PITCH + x] = (bf16 img[y][x], bf16 img[y][x+1]) packed.
    __shared__ __align__(16) unsigned tileU[PITCH * MAXNY];   // 37600 B

    int blk = blockIdx.x;
    int wc = blk & 7;
    int bv = blk >> 3;
    int v = bv % VIEWS;
    int b = bv / VIEWS;

    int tid = threadIdx.x;
    int lane = tid & 63;
    int g = tid >> 6;
    int w = wc * WCHUNK + lane;

    double ang = -3.14159265358979323846 * (double)(v + 1) / (double)VIEWS
                 - 3.14159265358979323846;
    float c = (float)cos(ang);
    float s = (float)sin(ang);

    const float* __restrict__ pimg = pad + (size_t)b * PH * PW;

    float xw = (float)w + 0.5f - 256.0f;
    float cxw = fmaf(c, xw, 255.5f);
    float sxw = fmaf(s, xw, 255.5f);

    // Per-thread valid-h interval (identical to validated rounds 2-6).
    float lo = -1e30f, hi = 1e30f;
    {
        float coef = -s, base = cxw;
        if (fabsf(coef) > 1e-6f) {
            float a = (-1.0f - base) / coef;
            float bq = (512.0f - base) / coef;
            lo = fmaxf(lo, fminf(a, bq));
            hi = fminf(hi, fmaxf(a, bq));
        } else if (!(base > -1.0f && base < 512.0f)) {
            lo = 1e30f; hi = -1e30f;
        }
    }
    {
        float coef = c, base = sxw;
        if (fabsf(coef) > 1e-6f) {
            float a = (-1.0f - base) / coef;
            float bq = (512.0f - base) / coef;
            lo = fmaxf(lo, fminf(a, bq));
            hi = fminf(hi, fmaxf(a, bq));
        } else if (!(base > -1.0f && base < 512.0f)) {
            lo = 1e30f; hi = -1e30f;
        }
    }
    float h0f = fminf(fmaxf(floorf(lo + 255.5f) - 1.0f, 0.0f), 512.0f);
    float h1f = fminf(fmaxf(ceilf(hi + 255.5f) + 1.0f, -1.0f), 511.0f);
    int h0 = (int)h0f;
    int h1 = (int)h1f;

    int bh0 = h0, bh1 = h1;
    #pragma unroll
    for (int m = 1; m < 64; m <<= 1) {
        bh0 = min(bh0, __shfl_xor(bh0, m, 64));
        bh1 = max(bh1, __shfl_xor(bh1, m, 64));
    }

    float xa = (float)(wc * WCHUNK) + 0.5f - 256.0f;
    float xb = xa + 63.0f;

    float acc = 0.0f;
    float step4x = -4.0f * s;
    float step4y = 4.0f * c;

    for (int hc = bh0; hc <= bh1; hc += KH) {
        int hend = min(hc + KH - 1, bh1);

        float ha = (float)hc - 255.5f;
        float hb = (float)hend - 255.5f;
        float ix00 = c * xa - s * ha, ix01 = c * xa - s * hb;
        float ix10 = c * xb - s * ha, ix11 = c * xb - s * hb;
        float iy00 = s * xa + c * ha, iy01 = s * xa + c * hb;
        float iy10 = s * xb + c * ha, iy11 = s * xb + c * hb;
        float ixmn = fminf(fminf(ix00, ix01), fminf(ix10, ix11)) + 255.5f;
        float iymn = fminf(fminf(iy00, iy01), fminf(iy10, iy11)) + 255.5f;
        float iymx = fmaxf(fmaxf(iy00, iy01), fmaxf(iy10, iy11)) + 255.5f;
        int x_lo = (int)floorf(ixmn) - 1;
        int x_lo4 = x_lo & ~3;
        int y_lo = (int)floorf(iymn) - 1;
        int NY = min((int)floorf(iymx) + 3 - y_lo, MAXNY);
        int total4 = NY * NXF4;
        int nit = (total4 + 255) >> 8;

        __syncthreads();

        // Maskless staging from padded image; convert to bf16 pairs.
        // float4 + neighbor -> 4 packed dwords -> one b128 LDS write.
        {
            const float* pb = pimg + (y_lo + PAD) * PW + (x_lo4 + PAD);
            for (int k = 0; k < nit; ++k) {
                int i = (k << 8) + tid;
                int ic = min(i, total4 - 1);          // dup lanes write same data
                int ry = ic / NXF4;                   // magic-mul (const 25)
                int rx4 = ic - ry * NXF4;
                const float* src = pb + 4 * ic + (PW - 4 * NXF4) * ry;
                float4 v4 = *(const float4*)src;
                float nx = src[4];
                __hip_bfloat162 p0 = __float22bfloat162_rn(make_float2(v4.x, v4.y));
                __hip_bfloat162 p1 = __float22bfloat162_rn(make_float2(v4.y, v4.z));
                __hip_bfloat162 p2 = __float22bfloat162_rn(make_float2(v4.z, v4.w));
                __hip_bfloat162 p3 = __float22bfloat162_rn(make_float2(v4.w, nx));
                uint4 d;
                d.x = *(unsigned*)&p0;
                d.y = *(unsigned*)&p1;
                d.z = *(unsigned*)&p2;
                d.w = *(unsigned*)&p3;
                *(uint4*)&tileU[ry * PITCH + (rx4 << 2)] = d;
            }
        }
        __syncthreads();

        // Gather: 2 dword reads per tap-pair (rows at +0 / +PITCH dwords;
        // const offsets -> ds_read2-mergeable). Unpack bf16 by shift/mask.
        float hh0 = (float)(hc + g) - 255.5f;
        float ixr = fmaf(-s, hh0, cxw) - (float)x_lo4;
        float iyr = fmaf(c, hh0, sxw) - (float)y_lo;
        #pragma unroll 4
        for (int h = hc + g; h <= hend; h += 4) {
            float fx = floorf(ixr);
            float fy = floorf(iyr);
            int lx = (int)fx;
            int ly = (int)fy;
            float wx1 = ixr - fx;
            float wy1 = iyr - fy;
            const unsigned* p = tileU + (ly * PITCH + lx);
            unsigned d0 = p[0];
            unsigned d1 = p[PITCH];
            float t00 = __uint_as_float(d0 << 16);
            float t01 = __uint_as_float(d0 & 0xffff0000u);
            float t10 = __uint_as_float(d1 << 16);
            float t11 = __uint_as_float(d1 & 0xffff0000u);
            float l0 = fmaf(wx1, t01 - t00, t00);
            float l1 = fmaf(wx1, t11 - t10, t10);
            acc = fmaf(wy1, l1 - l0, acc + l0);
            ixr += step4x;
            iyr += step4y;
        }
    }

    // Reduce the 4 h-phase partials, reusing the tile.
    __syncthreads();
    tileU[(g << 6) + lane] = __float_as_uint(acc);
    __syncthreads();
    if (g == 0) {
        float r = __uint_as_float(tileU[lane]) + __uint_as_float(tileU[64 + lane]) +
                  __uint_as_float(tileU[128 + lane]) + __uint_as_float(tileU[192 + lane]);
        out[((size_t)(b * IMGSZ + w)) * VIEWS + v] = r * 0.5f;
    }
}

extern "C" void kernel_launch(void* const* d_in, const int* in_sizes, int n_in,
                              void* d_out, int out_size, void* d_ws, size_t ws_size,
                              hipStream_t stream) {
    const float* x = (const float*)d_in[0];
    float* out = (float*)d_out;
    float* pad = (float*)d_ws;    // needs BATCH*PH*PW*4 = 4,009,984 bytes

    constexpr int padTotal = BATCH * PH * (PW / 4);
    pad_kernel<<<(padTotal + 255) / 256, 256, 0, stream>>>(x, pad);

    int nblocks = BATCH * VIEWS * (IMGSZ / WCHUNK);   // 5760
    fp_kernel<<<nblocks, 256, 0, stream>>>(pad, out);
}

// Round 9
// 212.725 us; speedup vs baseline: 1.2680x; 1.1600x over previous
//
#include <hip/hip_runtime.h>

typedef __fp16 h2 __attribute__((ext_vector_type(2)));

constexpr int VIEWS = 360;
constexpr int IMGSZ = 512;
constexpr int BATCH = 2;
constexpr int WCHUNK = 64;   // w per block
constexpr int KH = 64;       // h per LDS chunk
constexpr int NXF4 = 25;     // staged box width in 4-dword groups (100 texels)
constexpr int PITCH = 100;   // dwords (texel positions) per LDS row
constexpr int MAXNY = 94;    // max staged rows
constexpr int PW = 712;      // padded width in texel positions (dwords/row)
constexpr int PH = 704;      // padded height
constexpr int PAD = 96;

// ---------- pad kernel: zero-padded image as packed f16 PAIRS --------------
// padu[b][py][px] = (f16 img[py-PAD][px-PAD], f16 img[py-PAD][px-PAD+1])
__global__ __launch_bounds__(256) void pad_kernel(const float* __restrict__ x,
                                                  unsigned* __restrict__ padu) {
    constexpr int PW4 = PW / 4;              // 178 groups per row
    constexpr int perimg = PH * PW4;
    int idx = blockIdx.x * 256 + threadIdx.x;
    if (idx >= BATCH * perimg) return;
    int b = idx / perimg;
    int r = idx - b * perimg;
    int py = r / PW4;
    int px4 = r - py * PW4;
    int gx = px4 * 4 - PAD;
    int gy = py - PAD;
    const float* img = x + (size_t)b * IMGSZ * IMGSZ;
    bool rowok = (unsigned)gy < (unsigned)IMGSZ;
    float v[5];
    #pragma unroll
    for (int j = 0; j < 5; ++j) {
        int xx = gx + j;
        v[j] = (rowok && (unsigned)xx < (unsigned)IMGSZ) ? img[gy * IMGSZ + xx]
                                                         : 0.0f;
    }
    h2 p0 = __builtin_amdgcn_cvt_pkrtz(v[0], v[1]);
    h2 p1 = __builtin_amdgcn_cvt_pkrtz(v[1], v[2]);
    h2 p2 = __builtin_amdgcn_cvt_pkrtz(v[2], v[3]);
    h2 p3 = __builtin_amdgcn_cvt_pkrtz(v[3], v[4]);
    uint4 d;
    d.x = __builtin_bit_cast(unsigned, p0);
    d.y = __builtin_bit_cast(unsigned, p1);
    d.z = __builtin_bit_cast(unsigned, p2);
    d.w = __builtin_bit_cast(unsigned, p3);
    *(uint4*)&padu[(size_t)idx * 4] = d;
}

// ---------- main kernel: copy-only staging + fdot2 gather ------------------
__global__ __launch_bounds__(256) void fp_kernel(const unsigned* __restrict__ padu,
                                                 float* __restrict__ out) {
    __shared__ __align__(16) unsigned tileU[10240];   // 40960 B

    int blk = blockIdx.x;
    int wc = blk & 7;
    int bv = blk >> 3;
    int v = bv % VIEWS;
    int b = bv / VIEWS;

    int tid = threadIdx.x;
    int lane = tid & 63;
    int g = tid >> 6;
    int w = wc * WCHUNK + lane;

    double ang = -3.14159265358979323846 * (double)(v + 1) / (double)VIEWS
                 - 3.14159265358979323846;
    float c = (float)cos(ang);
    float s = (float)sin(ang);

    float xw = (float)w + 0.5f - 256.0f;
    float cxw = fmaf(c, xw, 255.5f);
    float sxw = fmaf(s, xw, 255.5f);

    // Per-thread valid-h interval (identical to validated rounds 2-7).
    float lo = -1e30f, hi = 1e30f;
    {
        float coef = -s, base = cxw;
        if (fabsf(coef) > 1e-6f) {
            float a = (-1.0f - base) / coef;
            float bq = (512.0f - base) / coef;
            lo = fmaxf(lo, fminf(a, bq));
            hi = fminf(hi, fmaxf(a, bq));
        } else if (!(base > -1.0f && base < 512.0f)) {
            lo = 1e30f; hi = -1e30f;
        }
    }
    {
        float coef = c, base = sxw;
        if (fabsf(coef) > 1e-6f) {
            float a = (-1.0f - base) / coef;
            float bq = (512.0f - base) / coef;
            lo = fmaxf(lo, fminf(a, bq));
            hi = fminf(hi, fmaxf(a, bq));
        } else if (!(base > -1.0f && base < 512.0f)) {
            lo = 1e30f; hi = -1e30f;
        }
    }
    float h0f = fminf(fmaxf(floorf(lo + 255.5f) - 1.0f, 0.0f), 512.0f);
    float h1f = fminf(fmaxf(ceilf(hi + 255.5f) + 1.0f, -1.0f), 511.0f);
    int h0 = (int)h0f;
    int h1 = (int)h1f;

    int bh0 = h0, bh1 = h1;
    #pragma unroll
    for (int m = 1; m < 64; m <<= 1) {
        bh0 = min(bh0, __shfl_xor(bh0, m, 64));
        bh1 = max(bh1, __shfl_xor(bh1, m, 64));
    }

    float xa = (float)(wc * WCHUNK) + 0.5f - 256.0f;
    float xb = xa + 63.0f;

    float acc = 0.0f;
    float step4x = -4.0f * s;
    float step4y = 4.0f * c;

    for (int hc = bh0; hc <= bh1; hc += KH) {
        int hend = min(hc + KH - 1, bh1);

        float ha = (float)hc - 255.5f;
        float hb = (float)hend - 255.5f;
        float ix00 = c * xa - s * ha, ix01 = c * xa - s * hb;
        float ix10 = c * xb - s * ha, ix11 = c * xb - s * hb;
        float iy00 = s * xa + c * ha, iy01 = s * xa + c * hb;
        float iy10 = s * xb + c * ha, iy11 = s * xb + c * hb;
        float ixmn = fminf(fminf(ix00, ix01), fminf(ix10, ix11)) + 255.5f;
        float iymn = fminf(fminf(iy00, iy01), fminf(iy10, iy11)) + 255.5f;
        float iymx = fmaxf(fmaxf(iy00, iy01), fmaxf(iy10, iy11)) + 255.5f;
        int x_lo = (int)floorf(ixmn) - 1;
        int x_lo4 = x_lo & ~3;
        int y_lo = (int)floorf(iymn) - 1;
        int NY = min((int)floorf(iymx) + 3 - y_lo, MAXNY);
        int total4 = NY * NXF4;
        int nit = (total4 + 255) >> 8;

        __syncthreads();

        // Copy-only staging: image is pre-packed as f16 pairs, in-bounds by
        // construction (x_lo,y_lo in [-92,511] -> window inside padded img).
        {
            const unsigned* pb = padu + (size_t)b * PH * PW
                               + (y_lo + PAD) * PW + (x_lo4 + PAD);
            for (int k = 0; k < nit; ++k) {
                int i = (k << 8) + tid;
                int ic = min(i, total4 - 1);
                int ry = ic / NXF4;                    // magic-mul (const 25)
                uint4 val = *(const uint4*)(pb + 4 * ic + (PW - 4 * NXF4) * ry);
                *(uint4*)&tileU[i << 2] = val;
            }
        }
        __syncthreads();

        // Gather: one ds_read2-mergeable dword pair per sample + 2 fdot2.
        float hh0 = (float)(hc + g) - 255.5f;
        float ixr = fmaf(-s, hh0, cxw) - (float)x_lo4;
        float iyr = fmaf(c, hh0, sxw) - (float)y_lo;
        #pragma unroll 4
        for (int h = hc + g; h <= hend; h += 4) {
            float fx = floorf(ixr);
            float fy = floorf(iyr);
            int lx = (int)fx;
            int ly = (int)fy;
            float wx1 = ixr - fx;
            float wy1 = iyr - fy;
            h2 wpk = __builtin_amdgcn_cvt_pkrtz(1.0f - wx1, wx1);
            const unsigned* p = tileU + (ly * PITCH + lx);
            unsigned d0 = p[0];
            unsigned d1 = p[PITCH];
            float l0 = __builtin_amdgcn_fdot2(__builtin_bit_cast(h2, d0), wpk,
                                              0.0f, false);
            float l1 = __builtin_amdgcn_fdot2(__builtin_bit_cast(h2, d1), wpk,
                                              0.0f, false);
            acc = fmaf(wy1, l1 - l0, acc + l0);
            ixr += step4x;
            iyr += step4y;
        }
    }

    // Reduce the 4 h-phase partials, reusing the tile.
    __syncthreads();
    tileU[(g << 6) + lane] = __float_as_uint(acc);
    __syncthreads();
    if (g == 0) {
        float r = __uint_as_float(tileU[lane]) + __uint_as_float(tileU[64 + lane]) +
                  __uint_as_float(tileU[128 + lane]) + __uint_as_float(tileU[192 + lane]);
        out[((size_t)(b * IMGSZ + w)) * VIEWS + v] = r * 0.5f;
    }
}

extern "C" void kernel_launch(void* const* d_in, const int* in_sizes, int n_in,
                              void* d_out, int out_size, void* d_ws, size_t ws_size,
                              hipStream_t stream) {
    const float* x = (const float*)d_in[0];
    float* out = (float*)d_out;
    unsigned* padu = (unsigned*)d_ws;   // BATCH*PH*PW*4 = 4,009,984 bytes

    constexpr int padTotal = BATCH * PH * (PW / 4);   // 250624 groups
    pad_kernel<<<(padTotal + 255) / 256, 256, 0, stream>>>(x, padu);

    int nblocks = BATCH * VIEWS * (IMGSZ / WCHUNK);   // 5760
    fp_kernel<<<nblocks, 256, 0, stream>>>(padu, out);
}

// Round 10
// 159.576 us; speedup vs baseline: 1.6904x; 1.3331x over previous
//
#include <hip/hip_runtime.h>

typedef __fp16 h2 __attribute__((ext_vector_type(2)));

constexpr int VIEWS = 360;
constexpr int IMGSZ = 512;
constexpr int BATCH = 2;
constexpr int WCHUNK = 64;   // w per block
constexpr int KH = 64;       // h per LDS chunk
constexpr int NXF4 = 25;     // staged box width in 4-dword groups (100 texels)
constexpr int PITCH = 100;   // dwords (texel positions) per LDS row
constexpr int MAXNY = 94;    // max staged rows
constexpr int PW = 712;      // padded width (dword positions per row)
constexpr int PH = 704;      // padded height
constexpr int PAD = 96;

// ---------- pad kernel: zero-padded, BATCH-PACKED f16 texels ---------------
// padq[py][px] = (f16 img_b0[py-PAD][px-PAD], f16 img_b1[py-PAD][px-PAD])
__global__ __launch_bounds__(256) void pad_kernel(const float* __restrict__ x,
                                                  unsigned* __restrict__ padq) {
    constexpr int PW4 = PW / 4;              // 178 groups per row
    constexpr int total = PH * PW4;          // 125312 groups
    int idx = blockIdx.x * 256 + threadIdx.x;
    if (idx >= total) return;
    int py = idx / PW4;
    int px4 = idx - py * PW4;
    int gx = px4 * 4 - PAD;                  // multiple of 4
    int gy = py - PAD;
    const float* img0 = x;
    const float* img1 = x + (size_t)IMGSZ * IMGSZ;
    bool rowok = (unsigned)gy < (unsigned)IMGSZ;
    float4 a = make_float4(0.f, 0.f, 0.f, 0.f);
    float4 bq = a;
    if (rowok && (unsigned)gx < (unsigned)IMGSZ) {   // gx%4==0 -> all-in/all-out
        a  = *(const float4*)(img0 + (size_t)gy * IMGSZ + gx);
        bq = *(const float4*)(img1 + (size_t)gy * IMGSZ + gx);
    }
    uint4 d;
    d.x = __builtin_bit_cast(unsigned, __builtin_amdgcn_cvt_pkrtz(a.x, bq.x));
    d.y = __builtin_bit_cast(unsigned, __builtin_amdgcn_cvt_pkrtz(a.y, bq.y));
    d.z = __builtin_bit_cast(unsigned, __builtin_amdgcn_cvt_pkrtz(a.z, bq.z));
    d.w = __builtin_bit_cast(unsigned, __builtin_amdgcn_cvt_pkrtz(a.w, bq.w));
    *(uint4*)&padq[(size_t)idx * 4] = d;
}

// ---------- main kernel: one block serves BOTH batches ---------------------
__global__ __launch_bounds__(256) void fp_kernel(const unsigned* __restrict__ padq,
                                                 float* __restrict__ out) {
    __shared__ __align__(16) unsigned tileU[10240];   // 40960 B

    int blk = blockIdx.x;          // 2880 = VIEWS * 8
    int wc = blk & 7;
    int v = blk >> 3;

    int tid = threadIdx.x;
    int lane = tid & 63;
    int g = tid >> 6;              // h phase 0..3
    int w = wc * WCHUNK + lane;

    double ang = -3.14159265358979323846 * (double)(v + 1) / (double)VIEWS
                 - 3.14159265358979323846;
    float c = (float)cos(ang);
    float s = (float)sin(ang);

    float xw = (float)w + 0.5f - 256.0f;
    float cxw = fmaf(c, xw, 255.5f);
    float sxw = fmaf(s, xw, 255.5f);

    // Per-thread valid-h interval (geometry only -> shared by both batches).
    float lo = -1e30f, hi = 1e30f;
    {
        float coef = -s, base = cxw;
        if (fabsf(coef) > 1e-6f) {
            float a = (-1.0f - base) / coef;
            float bq = (512.0f - base) / coef;
            lo = fmaxf(lo, fminf(a, bq));
            hi = fminf(hi, fmaxf(a, bq));
        } else if (!(base > -1.0f && base < 512.0f)) {
            lo = 1e30f; hi = -1e30f;
        }
    }
    {
        float coef = c, base = sxw;
        if (fabsf(coef) > 1e-6f) {
            float a = (-1.0f - base) / coef;
            float bq = (512.0f - base) / coef;
            lo = fmaxf(lo, fminf(a, bq));
            hi = fminf(hi, fmaxf(a, bq));
        } else if (!(base > -1.0f && base < 512.0f)) {
            lo = 1e30f; hi = -1e30f;
        }
    }
    float h0f = fminf(fmaxf(floorf(lo + 255.5f) - 1.0f, 0.0f), 512.0f);
    float h1f = fminf(fmaxf(ceilf(hi + 255.5f) + 1.0f, -1.0f), 511.0f);
    int h0 = (int)h0f;
    int h1 = (int)h1f;

    int bh0 = h0, bh1 = h1;
    #pragma unroll
    for (int m = 1; m < 64; m <<= 1) {
        bh0 = min(bh0, __shfl_xor(bh0, m, 64));
        bh1 = max(bh1, __shfl_xor(bh1, m, 64));
    }

    float xa = (float)(wc * WCHUNK) + 0.5f - 256.0f;
    float xb = xa + 63.0f;

    float acc0 = 0.0f, acc1 = 0.0f;   // f32 per-batch accumulators
    float step4x = -4.0f * s;
    float step4y = 4.0f * c;

    for (int hc = bh0; hc <= bh1; hc += KH) {
        int hend = min(hc + KH - 1, bh1);

        float ha = (float)hc - 255.5f;
        float hb = (float)hend - 255.5f;
        float ix00 = c * xa - s * ha, ix01 = c * xa - s * hb;
        float ix10 = c * xb - s * ha, ix11 = c * xb - s * hb;
        float iy00 = s * xa + c * ha, iy01 = s * xa + c * hb;
        float iy10 = s * xb + c * ha, iy11 = s * xb + c * hb;
        float ixmn = fminf(fminf(ix00, ix01), fminf(ix10, ix11)) + 255.5f;
        float iymn = fminf(fminf(iy00, iy01), fminf(iy10, iy11)) + 255.5f;
        float iymx = fmaxf(fmaxf(iy00, iy01), fmaxf(iy10, iy11)) + 255.5f;
        int x_lo = (int)floorf(ixmn) - 1;
        int x_lo4 = x_lo & ~3;
        int y_lo = (int)floorf(iymn) - 1;
        int NY = min((int)floorf(iymx) + 3 - y_lo, MAXNY);
        int total4 = NY * NXF4;
        int nit = (total4 + 255) >> 8;

        __syncthreads();

        // Copy-only staging of batch-packed texels (in-bounds by construction;
        // contiguous slot i == row-major with pitch 100).
        {
            const unsigned* pb = padq + (y_lo + PAD) * PW + (x_lo4 + PAD);
            for (int k = 0; k < nit; ++k) {
                int i = (k << 8) + tid;
                int ic = min(i, total4 - 1);
                int ry = ic / NXF4;                    // magic-mul (const 25)
                uint4 val = *(const uint4*)(pb + 4 * ic + (PW - 4 * NXF4) * ry);
                *(uint4*)&tileU[i << 2] = val;
            }
        }
        __syncthreads();

        // Gather: 2 x ds_read2_b32 per sample -> 4 batch-packed texels;
        // packed-f16 bilinear serves both batches at once.
        float hh0 = (float)(hc + g) - 255.5f;
        float ixr = fmaf(-s, hh0, cxw) - (float)x_lo4;
        float iyr = fmaf(c, hh0, sxw) - (float)y_lo;
        h2 accp0 = (h2)0.0f;
        h2 accp1 = (h2)0.0f;
        int parity = 0;
        #pragma unroll 4
        for (int h = hc + g; h <= hend; h += 4) {
            float fx = floorf(ixr);
            float fy = floorf(iyr);
            int lx = (int)fx;
            int ly = (int)fy;
            float wx1 = ixr - fx;
            float wy1 = iyr - fy;
            h2 wx0s = __builtin_amdgcn_cvt_pkrtz(1.0f - wx1, 1.0f - wx1);
            h2 wx1s = __builtin_amdgcn_cvt_pkrtz(wx1, wx1);
            h2 wy0s = __builtin_amdgcn_cvt_pkrtz(1.0f - wy1, 1.0f - wy1);
            h2 wy1s = __builtin_amdgcn_cvt_pkrtz(wy1, wy1);
            const unsigned* p = tileU + (ly * PITCH + lx);
            unsigned q00 = p[0];
            unsigned q01 = p[1];
            unsigned q10 = p[PITCH];
            unsigned q11 = p[PITCH + 1];
            h2 r0 = __builtin_bit_cast(h2, q00) * wx0s
                  + __builtin_bit_cast(h2, q01) * wx1s;
            h2 r1 = __builtin_bit_cast(h2, q10) * wx0s
                  + __builtin_bit_cast(h2, q11) * wx1s;
            h2 contrib = r0 * wy0s + r1 * wy1s;
            if (parity) accp1 += contrib; else accp0 += contrib;
            parity ^= 1;
            ixr += step4x;
            iyr += step4y;
        }
        // Flush chunk-local f16 partials to f32 (bounds f16 accum error).
        acc0 += (float)accp0.x + (float)accp1.x;
        acc1 += (float)accp0.y + (float)accp1.y;
    }

    // Reduce the 4 h-phase partials for both batches, reusing the tile.
    __syncthreads();
    tileU[(g << 6) + lane] = __float_as_uint(acc0);
    tileU[256 + (g << 6) + lane] = __float_as_uint(acc1);
    __syncthreads();
    if (g == 0) {
        float r0 = __uint_as_float(tileU[lane]) + __uint_as_float(tileU[64 + lane]) +
                   __uint_as_float(tileU[128 + lane]) + __uint_as_float(tileU[192 + lane]);
        float r1 = __uint_as_float(tileU[256 + lane]) + __uint_as_float(tileU[320 + lane]) +
                   __uint_as_float(tileU[384 + lane]) + __uint_as_float(tileU[448 + lane]);
        size_t o = (size_t)w * VIEWS + v;
        out[o] = r0 * 0.5f;
        out[(size_t)IMGSZ * VIEWS + o] = r1 * 0.5f;
    }
}

extern "C" void kernel_launch(void* const* d_in, const int* in_sizes, int n_in,
                              void* d_out, int out_size, void* d_ws, size_t ws_size,
                              hipStream_t stream) {
    const float* x = (const float*)d_in[0];
    float* out = (float*)d_out;
    unsigned* padq = (unsigned*)d_ws;   // PH*PW*4 = 2,004,992 bytes

    constexpr int padTotal = PH * (PW / 4);          // 125312 groups
    pad_kernel<<<(padTotal + 255) / 256, 256, 0, stream>>>(x, padq);

    int nblocks = VIEWS * (IMGSZ / WCHUNK);          // 2880
    fp_kernel<<<nblocks, 256, 0, stream>>>(padq, out);
}